// Round 12
// baseline (491.331 us; speedup 1.0000x reference)
//
#include <hip/hip_runtime.h>
#include <stdint.h>

#define NN 100000
#define NE 3200000
#define NG 2048
#define DH 128

#define NBUK 196       // dst >> 9 buckets (512 nodes each)
#define BSH 9
#define BMASK 511
#define BUKCAP 18200   // expected 16384 +- 128; +14 sigma safety
#define EPT 16         // edges per thread in partition_k
#define EPW 4096       // edges per workgroup

#define WLROW 132      // LDS row stride in shorts (264B = 66 dwords: staging
                       // writes hit all 32 banks; reads <=2-way = free)

typedef __attribute__((ext_vector_type(8))) short v8s;
typedef __attribute__((ext_vector_type(4))) float v4f;
typedef __attribute__((ext_vector_type(2))) float f2;

// ---------- helpers ----------
__device__ __forceinline__ float bf2f(unsigned short u) {
  union { unsigned int i; float f; } v; v.i = ((unsigned int)u) << 16; return v.f;
}
__device__ __forceinline__ unsigned short f2bf(float f) {
  union { float f; unsigned int i; } v; v.f = f;
  unsigned int i = v.i;
  unsigned int r = (i + 0x7FFFu + ((i >> 16) & 1u)) >> 16;
  return (unsigned short)r;
}
__device__ __forceinline__ int eload(const void* p, long long i, int is64) {
  return is64 ? (int)((const long long*)p)[i] : ((const int*)p)[i];
}
__device__ __forceinline__ float pload(const void* p, int i, int isbf) {
  return isbf ? bf2f(((const unsigned short*)p)[i]) : ((const float*)p)[i];
}
// unpack one dword (2 bf16) into float2 and accumulate (v_pk_add_f32 path)
__device__ __forceinline__ void upadd2(unsigned int w, f2& acc) {
  union { unsigned int u; float f; } a, b;
  a.u = w << 16; b.u = w & 0xffff0000u;
  f2 u; u.x = a.f; u.y = b.f;
  acc += u;
}
#define ACC4(v) do { upadd2((v).x, a01); upadd2((v).y, a23); \
                     upadd2((v).z, a45); upadd2((v).w, a67); } while (0)

// CSR-row gather: quarter-wave, up to 4 uint4 loads in flight (16 edges).
// 32-deep unroll measured WORSE (VGPR 40, occ 56%): service-rate wall, r10.
__device__ __forceinline__ void gather_row(const uint4* Hc, const int* colv,
    int beg, int end, int q, f2& a01, f2& a23, f2& a45, f2& a67) {
  int j = beg;
  for (; j + 16 <= end; j += 16) {
    int s0 = colv[j + q],     s1 = colv[j + 4 + q];
    int s2 = colv[j + 8 + q], s3 = colv[j + 12 + q];
    uint4 v0 = Hc[s0 * 16]; uint4 v1 = Hc[s1 * 16];
    uint4 v2 = Hc[s2 * 16]; uint4 v3 = Hc[s3 * 16];
    ACC4(v0); ACC4(v1); ACC4(v2); ACC4(v3);
  }
  for (; j + 4 <= end; j += 4) {
    uint4 v0 = Hc[colv[j + q] * 16];
    ACC4(v0);
  }
  if (j + q < end) {
    uint4 v0 = Hc[colv[j + q] * 16];
    ACC4(v0);
  }
}
#define WAVE_RED() do { \
  _Pragma("unroll") \
  for (int m = 16; m <= 32; m <<= 1) { \
    a01.x += __shfl_xor(a01.x, m); a01.y += __shfl_xor(a01.y, m); \
    a23.x += __shfl_xor(a23.x, m); a23.y += __shfl_xor(a23.y, m); \
    a45.x += __shfl_xor(a45.x, m); a45.y += __shfl_xor(a45.y, m); \
    a67.x += __shfl_xor(a67.x, m); a67.y += __shfl_xor(a67.y, m); \
  } } while (0)

// ---------- ws layout (lean: ~65.0 MB total) ----------
constexpr size_t al(size_t x) { return (x + 255) & ~size_t(255); }
constexpr size_t OFF_FLAGS = 0;                                   // int[8]
constexpr size_t OFF_DINV  = 256;                                 // float[NN]
constexpr size_t OFF_ROWP  = al(OFF_DINV + 4ull * NN);            // int[NN+1]
constexpr size_t OFF_GSTART= al(OFF_ROWP + 4ull * (NN + 1));      // int[NG+1]
constexpr size_t OFF_BCUR  = al(OFF_GSTART + 4ull * (NG + 1));    // int[256]
constexpr size_t OFF_WT    = al(OFF_BCUR + 1024);                 // ushort[3*16384]
constexpr size_t OFF_FC1W  = al(OFF_WT + 2ull * 3 * 16384);       // float[16384]
constexpr size_t OFF_FC2W  = al(OFF_FC1W + 4ull * 16384);         // float[256]
constexpr size_t OFF_PVEC  = al(OFF_FC2W + 4ull * 256);           // float[17*128]
constexpr size_t OFF_AC    = al(OFF_PVEC + 4ull * 17 * 128);      // float[3*2*128]
constexpr size_t OFF_COL   = al(OFF_AC + 4ull * 768);             // int[NE]; later: pooled+Z
constexpr size_t OFF_H     = al(OFF_COL + 4ull * NE);             // ushort[NN*128]; overlay: records
constexpr size_t OFF_Y     = al(OFF_H + 2ull * NN * 128);         // ushort[NN*128]
constexpr size_t WS_NEED   = OFF_Y + 2ull * NN * 128;             // ~65.0 MB
// overlay (dead before gemm layer 1 writes H):
constexpr size_t OFF_REC   = OFF_H;                               // u64[NBUK*BUKCAP] = 28.5 MB

// ---------- kernels ----------

// Detect dtypes at runtime + zero bcur.
__global__ __launch_bounds__(256) void probe_k(const void* edge, const void* batch,
                                               const void* x, int* flags, int* bcur) {
  __shared__ int cnt_e, cnt_b, cnt_f;
  int t = threadIdx.x;
  bcur[t] = 0;
  if (t == 0) { cnt_e = 0; cnt_b = 0; cnt_f = 0; }
  __syncthreads();
  int le = 0, lb = 0, lf = 0;
  for (int i = t; i < 512; i += 256) {        // edge pairs: int64 => high dword 0
    uint2 p = ((const uint2*)edge)[i + 64];
    if (p.y != 0) le++;
  }
  for (int i = t; i < 512; i += 256) {        // batch tail pairs (values ~2047 if int32)
    uint2 p = ((const uint2*)batch)[50000 - 512 + i];
    if (p.y != 0) lb++;
  }
  for (int i = t; i < 4096; i += 256) {       // bf16 N(0,1) never has exp-field >= 0x90
    unsigned short u = ((const unsigned short*)x)[i];
    int e = (u >> 7) & 0xFF;
    if (e >= 0x90) lf++;
  }
  atomicAdd(&cnt_e, le); atomicAdd(&cnt_b, lb); atomicAdd(&cnt_f, lf);
  __syncthreads();
  if (t == 0) {
    flags[0] = (cnt_e == 0);   // edges are int64
    flags[1] = (cnt_b == 0);   // batch is int64
    flags[2] = (cnt_f < 16);   // floats are bf16
    flags[3] = 1;              // constant "bf16 yes" for layers 2/3
  }
}

struct Ptrs { const void* p[22]; };  // d_in[3..24]

__global__ __launch_bounds__(256) void norm_param_k(Ptrs ptrs, const int* flags,
    unsigned short* Wt, float* fc1W, float* fc2W, float* pvec) {
  int isbf = flags[2];
  int idx = blockIdx.x * 256 + threadIdx.x;
  if (idx < 3 * 16384) {
    int l = idx / 16384, rem = idx % 16384;
    int c = rem >> 7, k = rem & 127;
    const void* W = ptrs.p[2 * l];                   // W1,W2,W3 = p[0],p[2],p[4]
    Wt[l * 16384 + c * DH + k] = f2bf(pload(W, k * DH + c, isbf));
  } else if (idx < 4 * 16384) {
    int jj = idx - 3 * 16384;
    fc1W[jj] = pload(ptrs.p[18], jj, isbf);          // fc1_W
  } else if (idx < 4 * 16384 + 256) {
    int jj = idx - 4 * 16384;
    fc2W[jj] = pload(ptrs.p[20], jj, isbf);          // fc2_W
  } else if (idx < 4 * 16384 + 256 + 17 * 128) {
    int jj = idx - (4 * 16384 + 256);
    int slot = jj >> 7, e = jj & 127;
    // slots: b1,b2,b3, bn1_{g,b,m,v}, bn2_{g,b,m,v}, bn3_{g,b,m,v}, fc1_b, fc2_b
    int pi = (slot < 3) ? (1 + 2 * slot) : (slot < 15) ? (slot + 3) : (slot == 15 ? 19 : 21);
    if (slot == 16 && e >= 2) return;
    pvec[slot * 128 + e] = pload(ptrs.p[pi], e, isbf);
  }
}

__global__ __launch_bounds__(256) void prep_k(const float* pvec, float* AC) {
  int idx = blockIdx.x * 256 + threadIdx.x;
  if (idx >= 384) return;
  int l = idx >> 7, d = idx & 127;
  float b  = pvec[l * 128 + d];
  float g  = pvec[(3 + 4 * l) * 128 + d];
  float bb = pvec[(4 + 4 * l) * 128 + d];
  float m  = pvec[(5 + 4 * l) * 128 + d];
  float v  = pvec[(6 + 4 * l) * 128 + d];
  float s = g * rsqrtf(v + 1e-5f);
  AC[l * 256 + d] = s;                         // A
  AC[l * 256 + 128 + d] = (b - m) * s + bb;    // C
}

// One pass over edges: bucket partition (NO global atomics beyond space
// reservation). TWO-PASS edge read (r11: buffering sv/dv[16] spilled to
// scratch, VGPR_Count 20 < 32 live => partition was scratch-latency-bound).
// Second read hits L2 (64KB/WG working set).
__global__ __launch_bounds__(256) void partition_k(const void* edge, const int* flags,
    int* bcur, unsigned long long* recs) {
  __shared__ int lhist[NBUK];
  __shared__ int lbase[NBUK];
  __shared__ int lrank[NBUK];
  int t = threadIdx.x;
  for (int b = t; b < NBUK; b += 256) { lhist[b] = 0; lrank[b] = 0; }
  __syncthreads();
  long long e0 = (long long)blockIdx.x * EPW;
  int f = flags[0];
  // pass A: histogram only (no buffering)
  #pragma unroll
  for (int k = 0; k < EPT; ++k) {
    long long e = e0 + k * 256 + t;
    if (e < NE) {
      int s = eload(edge, e, f);
      int d = eload(edge, NE + e, f);
      if ((unsigned)s < NN && (unsigned)d < NN)
        atomicAdd(&lhist[d >> BSH], 1);
    }
  }
  __syncthreads();
  for (int b = t; b < NBUK; b += 256)
    lbase[b] = atomicAdd(&bcur[b], lhist[b]);
  __syncthreads();
  // pass B: reload (L2-warm) + ranked append
  #pragma unroll
  for (int k = 0; k < EPT; ++k) {
    long long e = e0 + k * 256 + t;
    if (e < NE) {
      int s = eload(edge, e, f);
      int d = eload(edge, NE + e, f);
      if ((unsigned)s < NN && (unsigned)d < NN) {
        int b = d >> BSH;
        int r = atomicAdd(&lrank[b], 1);
        int pos = lbase[b] + r;
        if (pos < BUKCAP)
          recs[(size_t)b * BUKCAP + pos] =
              ((unsigned long long)(unsigned)d << 32) | (unsigned)s;
      }
    }
  }
}

// Fused CSR build: per bucket (contiguous 512-node range) do
//   bucket-start reduce -> LDS deg histogram -> LDS prefix scan -> rowp+dinv
//   -> LDS-cursor scatter of records into colv. Zero global atomics.
__global__ __launch_bounds__(256) void csr_build_k(const unsigned long long* recs,
    const int* bcur, int* rowp, int* colv, float* dinv) {
  __shared__ int lh[512];
  __shared__ int lcur[512];
  __shared__ int lts[256];
  __shared__ int lstart;
  int b = blockIdx.x, t = threadIdx.x;
  {
    int v = (t < b && t < NBUK) ? min(bcur[t], BUKCAP) : 0;
    lts[t] = v; __syncthreads();
    for (int off = 128; off > 0; off >>= 1) {
      if (t < off) lts[t] += lts[t + off];
      __syncthreads();
    }
    if (t == 0) lstart = lts[0];
  }
  for (int i = t; i < 512; i += 256) lh[i] = 0;
  __syncthreads();
  int cnt = min(bcur[b], BUKCAP);
  const unsigned long long* rb = recs + (size_t)b * BUKCAP;
  for (int i = t; i < cnt; i += 256)
    atomicAdd(&lh[(int)(rb[i] >> 32) & BMASK], 1);
  __syncthreads();
  int e0 = lh[2 * t], e1 = lh[2 * t + 1];
  lts[t] = e0 + e1; __syncthreads();
  for (int off = 1; off < 256; off <<= 1) {
    int x = (t >= off) ? lts[t - off] : 0;
    __syncthreads();
    lts[t] += x;
    __syncthreads();
  }
  int pre = lts[t] - (e0 + e1);
  int base = b << BSH;
  int n0 = base + 2 * t, n1 = base + 2 * t + 1;
  int r0 = lstart + pre, r1 = lstart + pre + e0;
  if (n0 < NN) { rowp[n0] = r0; dinv[n0] = rsqrtf((float)(e0 + 1)); }
  if (n1 < NN) { rowp[n1] = r1; dinv[n1] = rsqrtf((float)(e1 + 1)); }
  lcur[2 * t] = r0; lcur[2 * t + 1] = r1;
  if (b == NBUK - 1 && t == 255) rowp[NN] = lstart + lts[255];
  __syncthreads();
  for (int i = t; i < cnt; i += 256) {
    unsigned long long rec = rb[i];
    int d = (int)(rec >> 32);
    int s = (int)(rec & 0xffffffffu);
    int p = atomicAdd(&lcur[d & BMASK], 1);
    colv[p] = s;
  }
}

// batch is sorted: derive graph boundaries without atomics.
__global__ __launch_bounds__(256) void gbound_k(const void* batch, const int* flags,
                                                int* gstart) {
  int i = blockIdx.x * 256 + threadIdx.x;
  if (i >= NN) return;
  int f = flags[1];
  int b = eload(batch, i, f);
  if ((unsigned)b >= NG) b = NG - 1;
  int bp = -1;
  if (i > 0) {
    bp = eload(batch, i - 1, f);
    if ((unsigned)bp >= NG) bp = NG - 1;
  }
  for (int g = bp + 1; g <= b; ++g) gstart[g] = i;
  if (i == NN - 1) {
    for (int g = b + 1; g <= NG; ++g) gstart[g] = NN;
  }
}

// H[row][:] = dinv[row] * (A[row][:] @ W)  — MFMA 16x16x32 bf16.
// W staged once per block into LDS (264B row stride -> conflict-free writes).
__global__ __launch_bounds__(256) void gemm_k(const void* A, const int* flagp,
    const unsigned short* Wt, const float* dinv, unsigned short* H) {
  __shared__ unsigned short Wl[128 * WLROW];
  const int t = threadIdx.x;
  #pragma unroll
  for (int it = 0; it < 8; ++it) {
    int v = t + 256 * it;            // 0..2047 chunks of 16B
    int col = v >> 4, ch = v & 15;
    *(uint4*)&Wl[col * WLROW + ch * 8] = *(const uint4*)&Wt[col * DH + ch * 8];
  }
  const int wave = threadIdx.x >> 6;
  const int lane = threadIdx.x & 63;
  const int rowbase = blockIdx.x * 64 + wave * 16;
  const int r = lane & 15;
  const int g = lane >> 4;
  const int isb = flagp[0];
  int arow = rowbase + r;
  int arowc = (arow < NN) ? arow : 0;

  v8s a[4];
  if (isb) {
    const uint4* Ab = (const uint4*)A;
    #pragma unroll
    for (int ks = 0; ks < 4; ++ks) {
      union { uint4 u; v8s v; } t2;
      t2.u = Ab[(arowc * DH + ks * 32 + g * 8) >> 3];
      a[ks] = t2.v;
    }
  } else {
    const float4* Af = (const float4*)A;
    #pragma unroll
    for (int ks = 0; ks < 4; ++ks) {
      int bi = (arowc * DH + ks * 32 + g * 8) >> 2;
      float4 f0 = Af[bi], f1 = Af[bi + 1];
      v8s t2;
      t2[0]=(short)f2bf(f0.x); t2[1]=(short)f2bf(f0.y); t2[2]=(short)f2bf(f0.z); t2[3]=(short)f2bf(f0.w);
      t2[4]=(short)f2bf(f1.x); t2[5]=(short)f2bf(f1.y); t2[6]=(short)f2bf(f1.z); t2[7]=(short)f2bf(f1.w);
      a[ks] = t2;
    }
  }
  int orow0 = rowbase + g * 4;
  float dv[4];
  #pragma unroll
  for (int j = 0; j < 4; ++j) {
    int orow = orow0 + j;
    dv[j] = dinv[(orow < NN) ? orow : 0];
  }
  __syncthreads();
  #pragma unroll
  for (int ct = 0; ct < 8; ++ct) {
    v4f acc = {0.f, 0.f, 0.f, 0.f};
    #pragma unroll
    for (int ks = 0; ks < 4; ++ks) {
      union { uint4 u; v8s v; } t2;
      t2.u = *(const uint4*)&Wl[(ct * 16 + r) * WLROW + ks * 32 + g * 8];
      acc = __builtin_amdgcn_mfma_f32_16x16x32_bf16(a[ks], t2.v, acc, 0, 0, 0);
    }
    #pragma unroll
    for (int j = 0; j < 4; ++j) {
      int orow = orow0 + j;
      if (orow < NN) H[orow * DH + ct * 16 + r] = f2bf(acc[j] * dv[j]);
    }
  }
}

// Fused agg + next-layer GEMM, occupancy-preserving: 1024 threads = 16 waves,
// ONE NODE PER WAVE (full gather parallelism).
// Phase 1: wave w aggregates node base+w -> BN+ReLU row in LDS.
// Phase 2: waves 0..7 compute the 16-row MFMA GEMM (W in LDS), write Hout.
__global__ __launch_bounds__(1024, 8) void aggemm16_k(const unsigned short* H,
    const int* rowp, const int* colv, const float* dinv,
    const float* Avec, const float* Cvec, const unsigned short* Wt,
    unsigned short* Hout) {
  __shared__ unsigned short Wl[128 * WLROW];
  __shared__ unsigned short Ylds[16 * WLROW];
  const int t = threadIdx.x;
  #pragma unroll
  for (int it = 0; it < 2; ++it) {
    int v = t + 1024 * it;           // 0..2047 chunks of 16B
    int col = v >> 4, ch = v & 15;
    *(uint4*)&Wl[col * WLROW + ch * 8] = *(const uint4*)&Wt[col * DH + ch * 8];
  }
  const int wid = t >> 6, lane = t & 63;
  const int q = lane >> 4, c16 = lane & 15;
  const int base = blockIdx.x * 16;          // 6250*16 == NN exactly
  const int n = base + wid;
  const uint4* Hc = (const uint4*)H + c16;
  {
    f2 a01 = {0.f,0.f}, a23 = {0.f,0.f}, a45 = {0.f,0.f}, a67 = {0.f,0.f};
    gather_row(Hc, colv, rowp[n], rowp[n + 1], q, a01, a23, a45, a67);
    WAVE_RED();
    if (q == 0) {
      uint4 sv = Hc[n * 16];   // self term
      upadd2(sv.x, a01); upadd2(sv.y, a23);
      upadd2(sv.z, a45); upadd2(sv.w, a67);
      float dvn = dinv[n];
      int f0 = c16 * 8;
      float y0 = fmaxf(a01.x * dvn * Avec[f0+0] + Cvec[f0+0], 0.f);
      float y1 = fmaxf(a01.y * dvn * Avec[f0+1] + Cvec[f0+1], 0.f);
      float y2 = fmaxf(a23.x * dvn * Avec[f0+2] + Cvec[f0+2], 0.f);
      float y3 = fmaxf(a23.y * dvn * Avec[f0+3] + Cvec[f0+3], 0.f);
      float y4 = fmaxf(a45.x * dvn * Avec[f0+4] + Cvec[f0+4], 0.f);
      float y5 = fmaxf(a45.y * dvn * Avec[f0+5] + Cvec[f0+5], 0.f);
      float y6 = fmaxf(a67.x * dvn * Avec[f0+6] + Cvec[f0+6], 0.f);
      float y7 = fmaxf(a67.y * dvn * Avec[f0+7] + Cvec[f0+7], 0.f);
      uint4 o;
      o.x = (unsigned int)f2bf(y0) | ((unsigned int)f2bf(y1) << 16);
      o.y = (unsigned int)f2bf(y2) | ((unsigned int)f2bf(y3) << 16);
      o.z = (unsigned int)f2bf(y4) | ((unsigned int)f2bf(y5) << 16);
      o.w = (unsigned int)f2bf(y6) | ((unsigned int)f2bf(y7) << 16);
      *(uint4*)&Ylds[wid * WLROW + c16 * 8] = o;
    }
  }
  __syncthreads();
  if (wid < 8) {
    const int ct = wid;                      // column tile
    const int r = lane & 15, g = lane >> 4;
    v8s a[4];
    #pragma unroll
    for (int ks = 0; ks < 4; ++ks) {
      union { uint4 u; v8s v; } t2;
      t2.u = *(const uint4*)&Ylds[r * WLROW + ks * 32 + g * 8];
      a[ks] = t2.v;
    }
    v4f acc = {0.f, 0.f, 0.f, 0.f};
    #pragma unroll
    for (int ks = 0; ks < 4; ++ks) {
      union { uint4 u; v8s v; } t2;
      t2.u = *(const uint4*)&Wl[(ct * 16 + r) * WLROW + ks * 32 + g * 8];
      acc = __builtin_amdgcn_mfma_f32_16x16x32_bf16(a[ks], t2.v, acc, 0, 0, 0);
    }
    int orow0 = base + g * 4;
    #pragma unroll
    for (int j = 0; j < 4; ++j) {
      int orow = orow0 + j;
      Hout[orow * DH + ct * 16 + r] = f2bf(acc[j] * dinv[orow]);
    }
  }
}

// Final-layer aggregation (writes Y for pooling).
__global__ __launch_bounds__(256) void agg_k(const unsigned short* H, const int* rowp,
    const int* colv, const float* dinv, const float* Avec, const float* Cvec,
    unsigned short* Y) {
  int n = blockIdx.x * 4 + (threadIdx.x >> 6);
  if (n >= NN) return;
  int lane = threadIdx.x & 63;
  int q = lane >> 4;
  int c16 = lane & 15;
  const uint4* Hc = (const uint4*)H + c16;
  f2 a01 = {0.f,0.f}, a23 = {0.f,0.f}, a45 = {0.f,0.f}, a67 = {0.f,0.f};
  gather_row(Hc, colv, rowp[n], rowp[n + 1], q, a01, a23, a45, a67);
  WAVE_RED();
  if (q == 0) {
    uint4 sv = Hc[n * 16];   // self term
    upadd2(sv.x, a01); upadd2(sv.y, a23);
    upadd2(sv.z, a45); upadd2(sv.w, a67);
    float dvn = dinv[n];
    int f0 = c16 * 8;
    float y0 = fmaxf(a01.x * dvn * Avec[f0+0] + Cvec[f0+0], 0.f);
    float y1 = fmaxf(a01.y * dvn * Avec[f0+1] + Cvec[f0+1], 0.f);
    float y2 = fmaxf(a23.x * dvn * Avec[f0+2] + Cvec[f0+2], 0.f);
    float y3 = fmaxf(a23.y * dvn * Avec[f0+3] + Cvec[f0+3], 0.f);
    float y4 = fmaxf(a45.x * dvn * Avec[f0+4] + Cvec[f0+4], 0.f);
    float y5 = fmaxf(a45.y * dvn * Avec[f0+5] + Cvec[f0+5], 0.f);
    float y6 = fmaxf(a67.x * dvn * Avec[f0+6] + Cvec[f0+6], 0.f);
    float y7 = fmaxf(a67.y * dvn * Avec[f0+7] + Cvec[f0+7], 0.f);
    uint4 o;
    o.x = (unsigned int)f2bf(y0) | ((unsigned int)f2bf(y1) << 16);
    o.y = (unsigned int)f2bf(y2) | ((unsigned int)f2bf(y3) << 16);
    o.z = (unsigned int)f2bf(y4) | ((unsigned int)f2bf(y5) << 16);
    o.w = (unsigned int)f2bf(y6) | ((unsigned int)f2bf(y7) << 16);
    ((uint4*)Y)[n * 16 + c16] = o;
  }
}

// Pool: quarter-wave uint4 reads over the graph's contiguous row range.
__global__ __launch_bounds__(256) void pool_k(const unsigned short* Y, const int* gstart,
                                              float* pooled) {
  int g = blockIdx.x * 4 + (threadIdx.x >> 6);
  if (g >= NG) return;
  int lane = threadIdx.x & 63;
  int q = lane >> 4, c16 = lane & 15;
  const uint4* Yc = (const uint4*)Y + c16;
  int beg = gstart[g], end = gstart[g + 1];
  int cnt = end - beg;
  f2 a01 = {0.f,0.f}, a23 = {0.f,0.f}, a45 = {0.f,0.f}, a67 = {0.f,0.f};
  for (int i = beg + q; i < end; i += 4) {
    uint4 v = Yc[i * 16];
    ACC4(v);
  }
  WAVE_RED();
  if (q == 0) {
    float inv = 1.f / fmaxf((float)cnt, 1.f);
    float* pr = pooled + g * DH + c16 * 8;
    pr[0] = a01.x * inv; pr[1] = a01.y * inv;
    pr[2] = a23.x * inv; pr[3] = a23.y * inv;
    pr[4] = a45.x * inv; pr[5] = a45.y * inv;
    pr[6] = a67.x * inv; pr[7] = a67.y * inv;
  }
}

__global__ __launch_bounds__(256) void fc1_k(const float* pooled, const float* fc1W,
                                             const float* pvec, float* Z) {
  int idx = blockIdx.x * 256 + threadIdx.x;
  int g = idx >> 7, c = idx & 127;
  if (g >= NG) return;
  float acc = 0.f;
  const float* pr = pooled + g * DH;
  #pragma unroll 8
  for (int k = 0; k < DH; ++k) acc += pr[k] * fc1W[k * DH + c];
  acc += pvec[15 * 128 + c];
  Z[g * DH + c] = fmaxf(acc, 0.f);
}

__global__ __launch_bounds__(256) void fc2_k(const float* Z, const float* fc2W,
                                             const float* pvec, float* out) {
  int g = blockIdx.x * 256 + threadIdx.x;
  if (g >= NG) return;
  float l0 = pvec[16 * 128 + 0], l1 = pvec[16 * 128 + 1];
  const float* zr = Z + g * DH;
  #pragma unroll 8
  for (int k = 0; k < DH; ++k) { float z = zr[k]; l0 += z * fc2W[k * 2]; l1 += z * fc2W[k * 2 + 1]; }
  float m = fmaxf(l0, l1);
  float lse = m + logf(expf(l0 - m) + expf(l1 - m));
  out[g * 2]     = l0 - lse;
  out[g * 2 + 1] = l1 - lse;
}

// ---------- launch ----------
extern "C" void kernel_launch(void* const* d_in, const int* in_sizes, int n_in,
                              void* d_out, int out_size, void* d_ws, size_t ws_size,
                              hipStream_t stream) {
  char* ws = (char*)d_ws;
  int*   flags  = (int*)(ws + OFF_FLAGS);
  float* dinvp  = (float*)(ws + OFF_DINV);
  int*   rowp   = (int*)(ws + OFF_ROWP);
  int*   gstart = (int*)(ws + OFF_GSTART);
  int*   bcur   = (int*)(ws + OFF_BCUR);
  unsigned short* Wt  = (unsigned short*)(ws + OFF_WT);
  float* fc1W   = (float*)(ws + OFF_FC1W);
  float* fc2W   = (float*)(ws + OFF_FC2W);
  float* pvec   = (float*)(ws + OFF_PVEC);
  float* AC     = (float*)(ws + OFF_AC);
  int*   colv   = (int*)(ws + OFF_COL);
  unsigned short* Hbuf = (unsigned short*)(ws + OFF_H);
  unsigned short* Ybuf = (unsigned short*)(ws + OFF_Y);
  // Overlays: recs dead before gemm layer 1 writes H; pooled/Z overlay colv.
  unsigned long long* recs = (unsigned long long*)(ws + OFF_REC);
  float* pooled = (float*)(ws + OFF_COL);
  float* Z      = (float*)(ws + OFF_COL + 4ull * NG * DH);

  const void* x     = d_in[0];
  const void* edge  = d_in[1];
  const void* batch = d_in[2];

  probe_k<<<1, 256, 0, stream>>>(edge, batch, x, flags, bcur);

  Ptrs P;
  for (int i = 0; i < 22; ++i) P.p[i] = d_in[3 + i];
  norm_param_k<<<266, 256, 0, stream>>>(P, flags, Wt, fc1W, fc2W, pvec);
  prep_k<<<2, 256, 0, stream>>>(pvec, AC);

  partition_k<<<(NE + EPW - 1) / EPW, 256, 0, stream>>>(edge, flags, bcur, recs);
  gbound_k<<<(NN + 255) / 256, 256, 0, stream>>>(batch, flags, gstart);
  csr_build_k<<<NBUK, 256, 0, stream>>>(recs, bcur, rowp, colv, dinvp);

  const int GB = (NN + 63) / 64;   // 1563
  const int AB = NN / 16;          // 6250 (exact)
  // layer 1 gemm: x -> H1 (recs now dead)
  gemm_k<<<GB, 256, 0, stream>>>(x, flags + 2, Wt, dinvp, Hbuf);
  // fused agg1+BN+gemm2: H1 -> H2 (in Ybuf)
  aggemm16_k<<<AB, 1024, 0, stream>>>(Hbuf, rowp, colv, dinvp, AC, AC + 128,
                                      Wt + 16384, Ybuf);
  // fused agg2+BN+gemm3: H2 -> H3 (in Hbuf)
  aggemm16_k<<<AB, 1024, 0, stream>>>(Ybuf, rowp, colv, dinvp, AC + 256, AC + 384,
                                      Wt + 32768, Hbuf);
  // final agg: H3 -> Y
  agg_k<<<NN / 4, 256, 0, stream>>>(Hbuf, rowp, colv, dinvp, AC + 512, AC + 640, Ybuf);

  // colv region is now dead — reuse for pooled/Z.
  pool_k<<<NG / 4, 256, 0, stream>>>(Ybuf, gstart, pooled);
  fc1_k<<<(NG * DH) / 256, 256, 0, stream>>>(pooled, fc1W, pvec, Z);
  fc2_k<<<(NG + 255) / 256, 256, 0, stream>>>(Z, fc2W, pvec, (float*)d_out);
}

// Round 13
// 481.941 us; speedup vs baseline: 1.0195x; 1.0195x over previous
//
#include <hip/hip_runtime.h>
#include <stdint.h>

#define NN 100000
#define NE 3200000
#define NG 2048
#define DH 128

#define NBUK 196       // dst >> 9 buckets (512 nodes each)
#define BSH 9
#define BMASK 511
#define BUKCAP 18200   // expected 16384 +- 128; +14 sigma safety
#define EPT 16         // edges per thread in partition_k
#define EPW 4096       // edges per workgroup

#define WLROW 136      // LDS row stride in shorts (272B; measured best, r11)

typedef __attribute__((ext_vector_type(8))) short v8s;
typedef __attribute__((ext_vector_type(4))) float v4f;
typedef __attribute__((ext_vector_type(2))) float f2;

// ---------- helpers ----------
__device__ __forceinline__ float bf2f(unsigned short u) {
  union { unsigned int i; float f; } v; v.i = ((unsigned int)u) << 16; return v.f;
}
__device__ __forceinline__ unsigned short f2bf(float f) {
  union { float f; unsigned int i; } v; v.f = f;
  unsigned int i = v.i;
  unsigned int r = (i + 0x7FFFu + ((i >> 16) & 1u)) >> 16;
  return (unsigned short)r;
}
__device__ __forceinline__ int eload(const void* p, long long i, int is64) {
  return is64 ? (int)((const long long*)p)[i] : ((const int*)p)[i];
}
__device__ __forceinline__ float pload(const void* p, int i, int isbf) {
  return isbf ? bf2f(((const unsigned short*)p)[i]) : ((const float*)p)[i];
}
// unpack one dword (2 bf16) into float2 and accumulate (v_pk_add_f32 path)
__device__ __forceinline__ void upadd2(unsigned int w, f2& acc) {
  union { unsigned int u; float f; } a, b;
  a.u = w << 16; b.u = w & 0xffff0000u;
  f2 u; u.x = a.f; u.y = b.f;
  acc += u;
}
#define ACC4(v) do { upadd2((v).x, a01); upadd2((v).y, a23); \
                     upadd2((v).z, a45); upadd2((v).w, a67); } while (0)

// CSR-row gather: quarter-wave, up to 4 uint4 loads in flight (16 edges).
// 32-deep unroll measured WORSE (VGPR 40, occ 56%): service-rate wall, r10.
__device__ __forceinline__ void gather_row(const uint4* Hc, const int* colv,
    int beg, int end, int q, f2& a01, f2& a23, f2& a45, f2& a67) {
  int j = beg;
  for (; j + 16 <= end; j += 16) {
    int s0 = colv[j + q],     s1 = colv[j + 4 + q];
    int s2 = colv[j + 8 + q], s3 = colv[j + 12 + q];
    uint4 v0 = Hc[s0 * 16]; uint4 v1 = Hc[s1 * 16];
    uint4 v2 = Hc[s2 * 16]; uint4 v3 = Hc[s3 * 16];
    ACC4(v0); ACC4(v1); ACC4(v2); ACC4(v3);
  }
  for (; j + 4 <= end; j += 4) {
    uint4 v0 = Hc[colv[j + q] * 16];
    ACC4(v0);
  }
  if (j + q < end) {
    uint4 v0 = Hc[colv[j + q] * 16];
    ACC4(v0);
  }
}
#define WAVE_RED() do { \
  _Pragma("unroll") \
  for (int m = 16; m <= 32; m <<= 1) { \
    a01.x += __shfl_xor(a01.x, m); a01.y += __shfl_xor(a01.y, m); \
    a23.x += __shfl_xor(a23.x, m); a23.y += __shfl_xor(a23.y, m); \
    a45.x += __shfl_xor(a45.x, m); a45.y += __shfl_xor(a45.y, m); \
    a67.x += __shfl_xor(a67.x, m); a67.y += __shfl_xor(a67.y, m); \
  } } while (0)

// ---------- ws layout (lean: ~65.0 MB total) ----------
constexpr size_t al(size_t x) { return (x + 255) & ~size_t(255); }
constexpr size_t OFF_FLAGS = 0;                                   // int[8]
constexpr size_t OFF_DINV  = 256;                                 // float[NN]
constexpr size_t OFF_ROWP  = al(OFF_DINV + 4ull * NN);            // int[NN+1]
constexpr size_t OFF_GSTART= al(OFF_ROWP + 4ull * (NN + 1));      // int[NG+1]
constexpr size_t OFF_BCUR  = al(OFF_GSTART + 4ull * (NG + 1));    // int[256]
constexpr size_t OFF_WT    = al(OFF_BCUR + 1024);                 // ushort[3*16384]
constexpr size_t OFF_FC1W  = al(OFF_WT + 2ull * 3 * 16384);       // float[16384]
constexpr size_t OFF_FC2W  = al(OFF_FC1W + 4ull * 16384);         // float[256]
constexpr size_t OFF_PVEC  = al(OFF_FC2W + 4ull * 256);           // float[17*128]
constexpr size_t OFF_AC    = al(OFF_PVEC + 4ull * 17 * 128);      // float[3*2*128]
constexpr size_t OFF_COL   = al(OFF_AC + 4ull * 768);             // int[NE]; later: pooled+Z
constexpr size_t OFF_H     = al(OFF_COL + 4ull * NE);             // ushort[NN*128]; overlay: records
constexpr size_t OFF_Y     = al(OFF_H + 2ull * NN * 128);         // ushort[NN*128]
constexpr size_t WS_NEED   = OFF_Y + 2ull * NN * 128;             // ~65.0 MB
// overlay (dead before gemm layer 1 writes H):
constexpr size_t OFF_REC   = OFF_H;                               // u64[NBUK*BUKCAP] = 28.5 MB

// ---------- kernels ----------

// Detect dtypes at runtime + zero bcur.
__global__ __launch_bounds__(256) void probe_k(const void* edge, const void* batch,
                                               const void* x, int* flags, int* bcur) {
  __shared__ int cnt_e, cnt_b, cnt_f;
  int t = threadIdx.x;
  bcur[t] = 0;
  if (t == 0) { cnt_e = 0; cnt_b = 0; cnt_f = 0; }
  __syncthreads();
  int le = 0, lb = 0, lf = 0;
  for (int i = t; i < 512; i += 256) {        // edge pairs: int64 => high dword 0
    uint2 p = ((const uint2*)edge)[i + 64];
    if (p.y != 0) le++;
  }
  for (int i = t; i < 512; i += 256) {        // batch tail pairs (values ~2047 if int32)
    uint2 p = ((const uint2*)batch)[50000 - 512 + i];
    if (p.y != 0) lb++;
  }
  for (int i = t; i < 4096; i += 256) {       // bf16 N(0,1) never has exp-field >= 0x90
    unsigned short u = ((const unsigned short*)x)[i];
    int e = (u >> 7) & 0xFF;
    if (e >= 0x90) lf++;
  }
  atomicAdd(&cnt_e, le); atomicAdd(&cnt_b, lb); atomicAdd(&cnt_f, lf);
  __syncthreads();
  if (t == 0) {
    flags[0] = (cnt_e == 0);   // edges are int64
    flags[1] = (cnt_b == 0);   // batch is int64
    flags[2] = (cnt_f < 16);   // floats are bf16
    flags[3] = 1;              // constant "bf16 yes" for layers 2/3
  }
}

struct Ptrs { const void* p[22]; };  // d_in[3..24]

__global__ __launch_bounds__(256) void norm_param_k(Ptrs ptrs, const int* flags,
    unsigned short* Wt, float* fc1W, float* fc2W, float* pvec) {
  int isbf = flags[2];
  int idx = blockIdx.x * 256 + threadIdx.x;
  if (idx < 3 * 16384) {
    int l = idx / 16384, rem = idx % 16384;
    int c = rem >> 7, k = rem & 127;
    const void* W = ptrs.p[2 * l];                   // W1,W2,W3 = p[0],p[2],p[4]
    Wt[l * 16384 + c * DH + k] = f2bf(pload(W, k * DH + c, isbf));
  } else if (idx < 4 * 16384) {
    int jj = idx - 3 * 16384;
    fc1W[jj] = pload(ptrs.p[18], jj, isbf);          // fc1_W
  } else if (idx < 4 * 16384 + 256) {
    int jj = idx - 4 * 16384;
    fc2W[jj] = pload(ptrs.p[20], jj, isbf);          // fc2_W
  } else if (idx < 4 * 16384 + 256 + 17 * 128) {
    int jj = idx - (4 * 16384 + 256);
    int slot = jj >> 7, e = jj & 127;
    // slots: b1,b2,b3, bn1_{g,b,m,v}, bn2_{g,b,m,v}, bn3_{g,b,m,v}, fc1_b, fc2_b
    int pi = (slot < 3) ? (1 + 2 * slot) : (slot < 15) ? (slot + 3) : (slot == 15 ? 19 : 21);
    if (slot == 16 && e >= 2) return;
    pvec[slot * 128 + e] = pload(ptrs.p[pi], e, isbf);
  }
}

__global__ __launch_bounds__(256) void prep_k(const float* pvec, float* AC) {
  int idx = blockIdx.x * 256 + threadIdx.x;
  if (idx >= 384) return;
  int l = idx >> 7, d = idx & 127;
  float b  = pvec[l * 128 + d];
  float g  = pvec[(3 + 4 * l) * 128 + d];
  float bb = pvec[(4 + 4 * l) * 128 + d];
  float m  = pvec[(5 + 4 * l) * 128 + d];
  float v  = pvec[(6 + 4 * l) * 128 + d];
  float s = g * rsqrtf(v + 1e-5f);
  AC[l * 256 + d] = s;                         // A
  AC[l * 256 + 128 + d] = (b - m) * s + bb;    // C
}

// One pass over edges: bucket partition (NO global atomics beyond space reservation).
__global__ __launch_bounds__(256) void partition_k(const void* edge, const int* flags,
    int* bcur, unsigned long long* recs) {
  __shared__ int lhist[NBUK];
  __shared__ int lbase[NBUK];
  __shared__ int lrank[NBUK];
  int t = threadIdx.x;
  for (int b = t; b < NBUK; b += 256) { lhist[b] = 0; lrank[b] = 0; }
  __syncthreads();
  long long e0 = (long long)blockIdx.x * EPW;
  int f = flags[0];
  int sv[EPT], dv[EPT];
  #pragma unroll
  for (int k = 0; k < EPT; ++k) {
    long long e = e0 + k * 256 + t;
    int s = 0, d = -1;
    if (e < NE) {
      s = eload(edge, e, f);
      d = eload(edge, NE + e, f);
      if ((unsigned)s >= NN || (unsigned)d >= NN) d = -1;
    }
    sv[k] = s; dv[k] = d;
    if (d >= 0) atomicAdd(&lhist[d >> BSH], 1);
  }
  __syncthreads();
  for (int b = t; b < NBUK; b += 256)
    lbase[b] = atomicAdd(&bcur[b], lhist[b]);
  __syncthreads();
  #pragma unroll
  for (int k = 0; k < EPT; ++k) {
    int d = dv[k];
    if (d >= 0) {
      int b = d >> BSH;
      int r = atomicAdd(&lrank[b], 1);
      int pos = lbase[b] + r;
      if (pos < BUKCAP)
        recs[(size_t)b * BUKCAP + pos] =
            ((unsigned long long)(unsigned)d << 32) | (unsigned)sv[k];
    }
  }
}

// Fused CSR build: per bucket (contiguous 512-node range) do
//   bucket-start reduce -> LDS deg histogram -> LDS prefix scan -> rowp+dinv
//   -> LDS-cursor scatter of records into colv. Zero global atomics.
__global__ __launch_bounds__(256) void csr_build_k(const unsigned long long* recs,
    const int* bcur, int* rowp, int* colv, float* dinv) {
  __shared__ int lh[512];
  __shared__ int lcur[512];
  __shared__ int lts[256];
  __shared__ int lstart;
  int b = blockIdx.x, t = threadIdx.x;
  {
    int v = (t < b && t < NBUK) ? min(bcur[t], BUKCAP) : 0;
    lts[t] = v; __syncthreads();
    for (int off = 128; off > 0; off >>= 1) {
      if (t < off) lts[t] += lts[t + off];
      __syncthreads();
    }
    if (t == 0) lstart = lts[0];
  }
  for (int i = t; i < 512; i += 256) lh[i] = 0;
  __syncthreads();
  int cnt = min(bcur[b], BUKCAP);
  const unsigned long long* rb = recs + (size_t)b * BUKCAP;
  for (int i = t; i < cnt; i += 256)
    atomicAdd(&lh[(int)(rb[i] >> 32) & BMASK], 1);
  __syncthreads();
  int e0 = lh[2 * t], e1 = lh[2 * t + 1];
  lts[t] = e0 + e1; __syncthreads();
  for (int off = 1; off < 256; off <<= 1) {
    int x = (t >= off) ? lts[t - off] : 0;
    __syncthreads();
    lts[t] += x;
    __syncthreads();
  }
  int pre = lts[t] - (e0 + e1);
  int base = b << BSH;
  int n0 = base + 2 * t, n1 = base + 2 * t + 1;
  int r0 = lstart + pre, r1 = lstart + pre + e0;
  if (n0 < NN) { rowp[n0] = r0; dinv[n0] = rsqrtf((float)(e0 + 1)); }
  if (n1 < NN) { rowp[n1] = r1; dinv[n1] = rsqrtf((float)(e1 + 1)); }
  lcur[2 * t] = r0; lcur[2 * t + 1] = r1;
  if (b == NBUK - 1 && t == 255) rowp[NN] = lstart + lts[255];
  __syncthreads();
  for (int i = t; i < cnt; i += 256) {
    unsigned long long rec = rb[i];
    int d = (int)(rec >> 32);
    int s = (int)(rec & 0xffffffffu);
    int p = atomicAdd(&lcur[d & BMASK], 1);
    colv[p] = s;
  }
}

// batch is sorted: derive graph boundaries without atomics.
__global__ __launch_bounds__(256) void gbound_k(const void* batch, const int* flags,
                                                int* gstart) {
  int i = blockIdx.x * 256 + threadIdx.x;
  if (i >= NN) return;
  int f = flags[1];
  int b = eload(batch, i, f);
  if ((unsigned)b >= NG) b = NG - 1;
  int bp = -1;
  if (i > 0) {
    bp = eload(batch, i - 1, f);
    if ((unsigned)bp >= NG) bp = NG - 1;
  }
  for (int g = bp + 1; g <= b; ++g) gstart[g] = i;
  if (i == NN - 1) {
    for (int g = b + 1; g <= NG; ++g) gstart[g] = NN;
  }
}

// H[row][:] = dinv[row] * (A[row][:] @ W)  — MFMA 16x16x32 bf16.
// W staged once per block into LDS (272B row stride).
__global__ __launch_bounds__(256) void gemm_k(const void* A, const int* flagp,
    const unsigned short* Wt, const float* dinv, unsigned short* H) {
  __shared__ unsigned short Wl[128 * WLROW];
  const int t = threadIdx.x;
  #pragma unroll
  for (int it = 0; it < 8; ++it) {
    int v = t + 256 * it;            // 0..2047 chunks of 16B
    int col = v >> 4, ch = v & 15;
    *(uint4*)&Wl[col * WLROW + ch * 8] = *(const uint4*)&Wt[col * DH + ch * 8];
  }
  const int wave = threadIdx.x >> 6;
  const int lane = threadIdx.x & 63;
  const int rowbase = blockIdx.x * 64 + wave * 16;
  const int r = lane & 15;
  const int g = lane >> 4;
  const int isb = flagp[0];
  int arow = rowbase + r;
  int arowc = (arow < NN) ? arow : 0;

  v8s a[4];
  if (isb) {
    const uint4* Ab = (const uint4*)A;
    #pragma unroll
    for (int ks = 0; ks < 4; ++ks) {
      union { uint4 u; v8s v; } t2;
      t2.u = Ab[(arowc * DH + ks * 32 + g * 8) >> 3];
      a[ks] = t2.v;
    }
  } else {
    const float4* Af = (const float4*)A;
    #pragma unroll
    for (int ks = 0; ks < 4; ++ks) {
      int bi = (arowc * DH + ks * 32 + g * 8) >> 2;
      float4 f0 = Af[bi], f1 = Af[bi + 1];
      v8s t2;
      t2[0]=(short)f2bf(f0.x); t2[1]=(short)f2bf(f0.y); t2[2]=(short)f2bf(f0.z); t2[3]=(short)f2bf(f0.w);
      t2[4]=(short)f2bf(f1.x); t2[5]=(short)f2bf(f1.y); t2[6]=(short)f2bf(f1.z); t2[7]=(short)f2bf(f1.w);
      a[ks] = t2;
    }
  }
  int orow0 = rowbase + g * 4;
  float dv[4];
  #pragma unroll
  for (int j = 0; j < 4; ++j) {
    int orow = orow0 + j;
    dv[j] = dinv[(orow < NN) ? orow : 0];
  }
  __syncthreads();
  #pragma unroll
  for (int ct = 0; ct < 8; ++ct) {
    v4f acc = {0.f, 0.f, 0.f, 0.f};
    #pragma unroll
    for (int ks = 0; ks < 4; ++ks) {
      union { uint4 u; v8s v; } t2;
      t2.u = *(const uint4*)&Wl[(ct * 16 + r) * WLROW + ks * 32 + g * 8];
      acc = __builtin_amdgcn_mfma_f32_16x16x32_bf16(a[ks], t2.v, acc, 0, 0, 0);
    }
    #pragma unroll
    for (int j = 0; j < 4; ++j) {
      int orow = orow0 + j;
      if (orow < NN) H[orow * DH + ct * 16 + r] = f2bf(acc[j] * dv[j]);
    }
  }
}

// Fused agg + next-layer GEMM, occupancy-preserving: 1024 threads = 16 waves,
// ONE NODE PER WAVE (full gather parallelism).
// Phase 1: wave w aggregates node base+w -> BN+ReLU row in LDS.
// Phase 2: waves 0..7 compute the 16-row MFMA GEMM (W in LDS), write Hout.
__global__ __launch_bounds__(1024, 8) void aggemm16_k(const unsigned short* H,
    const int* rowp, const int* colv, const float* dinv,
    const float* Avec, const float* Cvec, const unsigned short* Wt,
    unsigned short* Hout) {
  __shared__ unsigned short Wl[128 * WLROW];
  __shared__ unsigned short Ylds[16 * WLROW];
  const int t = threadIdx.x;
  #pragma unroll
  for (int it = 0; it < 2; ++it) {
    int v = t + 1024 * it;           // 0..2047 chunks of 16B
    int col = v >> 4, ch = v & 15;
    *(uint4*)&Wl[col * WLROW + ch * 8] = *(const uint4*)&Wt[col * DH + ch * 8];
  }
  const int wid = t >> 6, lane = t & 63;
  const int q = lane >> 4, c16 = lane & 15;
  const int base = blockIdx.x * 16;          // 6250*16 == NN exactly
  const int n = base + wid;
  const uint4* Hc = (const uint4*)H + c16;
  {
    f2 a01 = {0.f,0.f}, a23 = {0.f,0.f}, a45 = {0.f,0.f}, a67 = {0.f,0.f};
    gather_row(Hc, colv, rowp[n], rowp[n + 1], q, a01, a23, a45, a67);
    WAVE_RED();
    if (q == 0) {
      uint4 sv = Hc[n * 16];   // self term
      upadd2(sv.x, a01); upadd2(sv.y, a23);
      upadd2(sv.z, a45); upadd2(sv.w, a67);
      float dvn = dinv[n];
      int f0 = c16 * 8;
      float y0 = fmaxf(a01.x * dvn * Avec[f0+0] + Cvec[f0+0], 0.f);
      float y1 = fmaxf(a01.y * dvn * Avec[f0+1] + Cvec[f0+1], 0.f);
      float y2 = fmaxf(a23.x * dvn * Avec[f0+2] + Cvec[f0+2], 0.f);
      float y3 = fmaxf(a23.y * dvn * Avec[f0+3] + Cvec[f0+3], 0.f);
      float y4 = fmaxf(a45.x * dvn * Avec[f0+4] + Cvec[f0+4], 0.f);
      float y5 = fmaxf(a45.y * dvn * Avec[f0+5] + Cvec[f0+5], 0.f);
      float y6 = fmaxf(a67.x * dvn * Avec[f0+6] + Cvec[f0+6], 0.f);
      float y7 = fmaxf(a67.y * dvn * Avec[f0+7] + Cvec[f0+7], 0.f);
      uint4 o;
      o.x = (unsigned int)f2bf(y0) | ((unsigned int)f2bf(y1) << 16);
      o.y = (unsigned int)f2bf(y2) | ((unsigned int)f2bf(y3) << 16);
      o.z = (unsigned int)f2bf(y4) | ((unsigned int)f2bf(y5) << 16);
      o.w = (unsigned int)f2bf(y6) | ((unsigned int)f2bf(y7) << 16);
      *(uint4*)&Ylds[wid * WLROW + c16 * 8] = o;
    }
  }
  __syncthreads();
  if (wid < 8) {
    const int ct = wid;                      // column tile
    const int r = lane & 15, g = lane >> 4;
    v8s a[4];
    #pragma unroll
    for (int ks = 0; ks < 4; ++ks) {
      union { uint4 u; v8s v; } t2;
      t2.u = *(const uint4*)&Ylds[r * WLROW + ks * 32 + g * 8];
      a[ks] = t2.v;
    }
    v4f acc = {0.f, 0.f, 0.f, 0.f};
    #pragma unroll
    for (int ks = 0; ks < 4; ++ks) {
      union { uint4 u; v8s v; } t2;
      t2.u = *(const uint4*)&Wl[(ct * 16 + r) * WLROW + ks * 32 + g * 8];
      acc = __builtin_amdgcn_mfma_f32_16x16x32_bf16(a[ks], t2.v, acc, 0, 0, 0);
    }
    int orow0 = base + g * 4;
    #pragma unroll
    for (int j = 0; j < 4; ++j) {
      int orow = orow0 + j;
      Hout[orow * DH + ct * 16 + r] = f2bf(acc[j] * dinv[orow]);
    }
  }
}

// Final-layer aggregation (writes Y for pooling).
__global__ __launch_bounds__(256) void agg_k(const unsigned short* H, const int* rowp,
    const int* colv, const float* dinv, const float* Avec, const float* Cvec,
    unsigned short* Y) {
  int n = blockIdx.x * 4 + (threadIdx.x >> 6);
  if (n >= NN) return;
  int lane = threadIdx.x & 63;
  int q = lane >> 4;
  int c16 = lane & 15;
  const uint4* Hc = (const uint4*)H + c16;
  f2 a01 = {0.f,0.f}, a23 = {0.f,0.f}, a45 = {0.f,0.f}, a67 = {0.f,0.f};
  gather_row(Hc, colv, rowp[n], rowp[n + 1], q, a01, a23, a45, a67);
  WAVE_RED();
  if (q == 0) {
    uint4 sv = Hc[n * 16];   // self term
    upadd2(sv.x, a01); upadd2(sv.y, a23);
    upadd2(sv.z, a45); upadd2(sv.w, a67);
    float dvn = dinv[n];
    int f0 = c16 * 8;
    float y0 = fmaxf(a01.x * dvn * Avec[f0+0] + Cvec[f0+0], 0.f);
    float y1 = fmaxf(a01.y * dvn * Avec[f0+1] + Cvec[f0+1], 0.f);
    float y2 = fmaxf(a23.x * dvn * Avec[f0+2] + Cvec[f0+2], 0.f);
    float y3 = fmaxf(a23.y * dvn * Avec[f0+3] + Cvec[f0+3], 0.f);
    float y4 = fmaxf(a45.x * dvn * Avec[f0+4] + Cvec[f0+4], 0.f);
    float y5 = fmaxf(a45.y * dvn * Avec[f0+5] + Cvec[f0+5], 0.f);
    float y6 = fmaxf(a67.x * dvn * Avec[f0+6] + Cvec[f0+6], 0.f);
    float y7 = fmaxf(a67.y * dvn * Avec[f0+7] + Cvec[f0+7], 0.f);
    uint4 o;
    o.x = (unsigned int)f2bf(y0) | ((unsigned int)f2bf(y1) << 16);
    o.y = (unsigned int)f2bf(y2) | ((unsigned int)f2bf(y3) << 16);
    o.z = (unsigned int)f2bf(y4) | ((unsigned int)f2bf(y5) << 16);
    o.w = (unsigned int)f2bf(y6) | ((unsigned int)f2bf(y7) << 16);
    ((uint4*)Y)[n * 16 + c16] = o;
  }
}

// Pool: quarter-wave uint4 reads over the graph's contiguous row range.
__global__ __launch_bounds__(256) void pool_k(const unsigned short* Y, const int* gstart,
                                              float* pooled) {
  int g = blockIdx.x * 4 + (threadIdx.x >> 6);
  if (g >= NG) return;
  int lane = threadIdx.x & 63;
  int q = lane >> 4, c16 = lane & 15;
  const uint4* Yc = (const uint4*)Y + c16;
  int beg = gstart[g], end = gstart[g + 1];
  int cnt = end - beg;
  f2 a01 = {0.f,0.f}, a23 = {0.f,0.f}, a45 = {0.f,0.f}, a67 = {0.f,0.f};
  for (int i = beg + q; i < end; i += 4) {
    uint4 v = Yc[i * 16];
    ACC4(v);
  }
  WAVE_RED();
  if (q == 0) {
    float inv = 1.f / fmaxf((float)cnt, 1.f);
    float* pr = pooled + g * DH + c16 * 8;
    pr[0] = a01.x * inv; pr[1] = a01.y * inv;
    pr[2] = a23.x * inv; pr[3] = a23.y * inv;
    pr[4] = a45.x * inv; pr[5] = a45.y * inv;
    pr[6] = a67.x * inv; pr[7] = a67.y * inv;
  }
}

__global__ __launch_bounds__(256) void fc1_k(const float* pooled, const float* fc1W,
                                             const float* pvec, float* Z) {
  int idx = blockIdx.x * 256 + threadIdx.x;
  int g = idx >> 7, c = idx & 127;
  if (g >= NG) return;
  float acc = 0.f;
  const float* pr = pooled + g * DH;
  #pragma unroll 8
  for (int k = 0; k < DH; ++k) acc += pr[k] * fc1W[k * DH + c];
  acc += pvec[15 * 128 + c];
  Z[g * DH + c] = fmaxf(acc, 0.f);
}

__global__ __launch_bounds__(256) void fc2_k(const float* Z, const float* fc2W,
                                             const float* pvec, float* out) {
  int g = blockIdx.x * 256 + threadIdx.x;
  if (g >= NG) return;
  float l0 = pvec[16 * 128 + 0], l1 = pvec[16 * 128 + 1];
  const float* zr = Z + g * DH;
  #pragma unroll 8
  for (int k = 0; k < DH; ++k) { float z = zr[k]; l0 += z * fc2W[k * 2]; l1 += z * fc2W[k * 2 + 1]; }
  float m = fmaxf(l0, l1);
  float lse = m + logf(expf(l0 - m) + expf(l1 - m));
  out[g * 2]     = l0 - lse;
  out[g * 2 + 1] = l1 - lse;
}

// ---------- launch ----------
extern "C" void kernel_launch(void* const* d_in, const int* in_sizes, int n_in,
                              void* d_out, int out_size, void* d_ws, size_t ws_size,
                              hipStream_t stream) {
  char* ws = (char*)d_ws;
  int*   flags  = (int*)(ws + OFF_FLAGS);
  float* dinvp  = (float*)(ws + OFF_DINV);
  int*   rowp   = (int*)(ws + OFF_ROWP);
  int*   gstart = (int*)(ws + OFF_GSTART);
  int*   bcur   = (int*)(ws + OFF_BCUR);
  unsigned short* Wt  = (unsigned short*)(ws + OFF_WT);
  float* fc1W   = (float*)(ws + OFF_FC1W);
  float* fc2W   = (float*)(ws + OFF_FC2W);
  float* pvec   = (float*)(ws + OFF_PVEC);
  float* AC     = (float*)(ws + OFF_AC);
  int*   colv   = (int*)(ws + OFF_COL);
  unsigned short* Hbuf = (unsigned short*)(ws + OFF_H);
  unsigned short* Ybuf = (unsigned short*)(ws + OFF_Y);
  // Overlays: recs dead before gemm layer 1 writes H; pooled/Z overlay colv.
  unsigned long long* recs = (unsigned long long*)(ws + OFF_REC);
  float* pooled = (float*)(ws + OFF_COL);
  float* Z      = (float*)(ws + OFF_COL + 4ull * NG * DH);

  const void* x     = d_in[0];
  const void* edge  = d_in[1];
  const void* batch = d_in[2];

  probe_k<<<1, 256, 0, stream>>>(edge, batch, x, flags, bcur);

  Ptrs P;
  for (int i = 0; i < 22; ++i) P.p[i] = d_in[3 + i];
  norm_param_k<<<266, 256, 0, stream>>>(P, flags, Wt, fc1W, fc2W, pvec);
  prep_k<<<2, 256, 0, stream>>>(pvec, AC);

  partition_k<<<(NE + EPW - 1) / EPW, 256, 0, stream>>>(edge, flags, bcur, recs);
  gbound_k<<<(NN + 255) / 256, 256, 0, stream>>>(batch, flags, gstart);
  csr_build_k<<<NBUK, 256, 0, stream>>>(recs, bcur, rowp, colv, dinvp);

  const int GB = (NN + 63) / 64;   // 1563
  const int AB = NN / 16;          // 6250 (exact)
  // layer 1 gemm: x -> H1 (recs now dead)
  gemm_k<<<GB, 256, 0, stream>>>(x, flags + 2, Wt, dinvp, Hbuf);
  // fused agg1+BN+gemm2: H1 -> H2 (in Ybuf)
  aggemm16_k<<<AB, 1024, 0, stream>>>(Hbuf, rowp, colv, dinvp, AC, AC + 128,
                                      Wt + 16384, Ybuf);
  // fused agg2+BN+gemm3: H2 -> H3 (in Hbuf)
  aggemm16_k<<<AB, 1024, 0, stream>>>(Ybuf, rowp, colv, dinvp, AC + 256, AC + 384,
                                      Wt + 32768, Hbuf);
  // final agg: H3 -> Y
  agg_k<<<NN / 4, 256, 0, stream>>>(Hbuf, rowp, colv, dinvp, AC + 512, AC + 640, Ybuf);

  // colv region is now dead — reuse for pooled/Z.
  pool_k<<<NG / 4, 256, 0, stream>>>(Ybuf, gstart, pooled);
  fc1_k<<<(NG * DH) / 256, 256, 0, stream>>>(pooled, fc1W, pvec, Z);
  fc2_k<<<(NG + 255) / 256, 256, 0, stream>>>(Z, fc2W, pvec, (float*)d_out);
}